// Round 3
// baseline (372.211 us; speedup 1.0000x reference)
//
#include <hip/hip_runtime.h>
#include <hip/hip_bf16.h>

typedef _Float16 f16;
typedef _Float16 f16x8 __attribute__((ext_vector_type(8)));
typedef _Float16 f16x4 __attribute__((ext_vector_type(4)));
typedef float f32x4 __attribute__((ext_vector_type(4)));

#define MFMA16(a, b, c) __builtin_amdgcn_mfma_f32_16x16x32_f16(a, b, c, 0, 0, 0)

static constexpr int S  = 4096;
static constexpr int NB = 4;    // batches

// ---------------------------------------------------------------------------
// Weight convert + transpose: Wt[n][k] = (f16) W[k][n]   (256x256)
// ---------------------------------------------------------------------------
__global__ void wconv_kernel(const float* __restrict__ W, f16* __restrict__ Wt) {
    int k = blockIdx.x;      // 0..255
    int n = threadIdx.x;     // 0..255
    Wt[n * 256 + k] = (f16)W[k * 256 + n];
}

// ---------------------------------------------------------------------------
// Projection GEMM: O[m][n] = epilogue( sum_k A[m][k] * Wt[n][k] + bias[n] )
// M = 16384, N = 256, K = 256.  Block: 256 thr (4 waves), BM = 32 rows/block.
// ASRC: 0 = A is fp32 (convert on the fly), 1 = A is f16.
// OMODE: 0 = store f16 row-major; 1 = cos() then store f16 row-major;
//        2 = store f16 TRANSPOSED per batch: O[(bi*256 + n)*S + s]
// ---------------------------------------------------------------------------
template <int ASRC, int OMODE>
__global__ __launch_bounds__(256) void proj_kernel(
    const float* __restrict__ Af, const f16* __restrict__ Ah,
    const f16* __restrict__ Wt, const float* __restrict__ bias,
    f16* __restrict__ O)
{
    int mbase = blockIdx.x * 32;
    int tid = threadIdx.x;
    int w = tid >> 6, l = tid & 63;
    int lr = l & 15, lg = l >> 4;
    int nbase = w * 64;

    f32x4 acc[2][4];
#pragma unroll
    for (int mf = 0; mf < 2; ++mf)
#pragma unroll
        for (int nf = 0; nf < 4; ++nf) acc[mf][nf] = f32x4{0.f, 0.f, 0.f, 0.f};

#pragma unroll
    for (int ks = 0; ks < 8; ++ks) {
        int kof = ks * 32 + lg * 8;
        f16x8 a[2], b[4];
#pragma unroll
        for (int mf = 0; mf < 2; ++mf) {
            int row = mbase + mf * 16 + lr;
            if (ASRC == 0) {
                const float4* p = (const float4*)(Af + row * 256 + kof);
                float4 x0 = p[0], x1 = p[1];
                f16x8 t;
                t[0] = (f16)x0.x; t[1] = (f16)x0.y; t[2] = (f16)x0.z; t[3] = (f16)x0.w;
                t[4] = (f16)x1.x; t[5] = (f16)x1.y; t[6] = (f16)x1.z; t[7] = (f16)x1.w;
                a[mf] = t;
            } else {
                a[mf] = *(const f16x8*)(Ah + row * 256 + kof);
            }
        }
#pragma unroll
        for (int nf = 0; nf < 4; ++nf) {
            int col = nbase + nf * 16 + lr;
            b[nf] = *(const f16x8*)(Wt + col * 256 + kof);
        }
#pragma unroll
        for (int mf = 0; mf < 2; ++mf)
#pragma unroll
            for (int nf = 0; nf < 4; ++nf)
                acc[mf][nf] = MFMA16(a[mf], b[nf], acc[mf][nf]);
    }

    // epilogue. C/D layout: col = lane&15, row = (lane>>4)*4 + reg  [HW-verified]
#pragma unroll
    for (int mf = 0; mf < 2; ++mf) {
#pragma unroll
        for (int nf = 0; nf < 4; ++nf) {
            int col = nbase + nf * 16 + lr;
            float bv = bias[col];
            if (OMODE <= 1) {
#pragma unroll
                for (int r = 0; r < 4; ++r) {
                    int row = mbase + mf * 16 + lg * 4 + r;
                    float x = acc[mf][nf][r] + bv;
                    if (OMODE == 1) x = cosf(x);
                    O[row * 256 + col] = (f16)x;
                }
            } else {
                int bi = mbase >> 12;                       // S = 4096, BM=32 | S
                int s  = (mbase & (S - 1)) + mf * 16 + lg * 4;
                f16x4 v;
#pragma unroll
                for (int r = 0; r < 4; ++r) v[r] = (f16)(acc[mf][nf][r] + bv);
                *(f16x4*)(O + ((bi * 256 + col) * S + s)) = v;
            }
        }
    }
}

// ---------------------------------------------------------------------------
// Flash attention, 8 waves/block, in-block 2-way key split.
//   waves 0-3 (group 0): keys 0..2047; waves 4-7 (group 1): keys 2048..4095.
//   Wave wg in each group owns q-rows qbase + wg*16 .. +16.  KBLK = 32.
//   K-hat tile per group single-buffered in LDS with register prefetch.
//   V read直接 from global (L1/L2-resident) -> no V staging, no 2nd buffer.
//   Softmax: defer-max (__any ballot, threshold 8), per-lane partial denom
//   (one shuffle-reduce at the END only).  In-LDS merge epilogue.
// Grid: 256 blocks.  bid&7 -> XCD; batch b = (bid>>1)&3 pins to 2 XCDs.
// ---------------------------------------------------------------------------
__global__ __launch_bounds__(512, 2) void attn_kernel(
    const f16* __restrict__ Qf, const f16* __restrict__ Hf,
    const f16* __restrict__ Vt, float* __restrict__ Out)
{
    // LDS pool, loop phase: KhS[2][32][264] f16 (33792 B) + PS[8][16][40] f16
    // epilogue overlay:     MrgF[4][16][130] f32 (33280 B) + ML[8][16][2] f32
    __shared__ __align__(16) char ldsp[44032];
    f16 (*KhS)[32][264]   = (f16(*)[32][264])ldsp;
    f16 (*PS)[16][40]     = (f16(*)[16][40])(ldsp + 33792);
    float (*MrgF)[16][130] = (float(*)[16][130])ldsp;
    float (*ML)[16][2]     = (float(*)[16][2])(ldsp + 33280);

    int bid = blockIdx.x;
    int b   = (bid >> 1) & 3;
    int qi  = ((bid >> 3) << 1) | (bid & 1);
    int qbase = qi * 64;

    int tid = threadIdx.x;
    int w  = tid >> 6, l = tid & 63;
    int g  = w >> 2, wg = w & 3;
    int lr = l & 15, lg = l >> 4;
    int qb = qbase + wg * 16;
    int kbase = g * 2048;

    // staging indices (256 threads per group stage the group's 32x256 tile)
    int gt = tid & 255;
    int krow[4], kc[4];
#pragma unroll
    for (int i = 0; i < 4; ++i) {
        int c = i * 256 + gt;
        krow[i] = c >> 5;
        kc[i]   = c & 31;
    }

    // Q fragments for this wave's 16 rows
    f16x8 qf[8];
    {
        const f16* qp = Qf + (b * S + qb + lr) * 256 + lg * 8;
#pragma unroll
        for (int ks = 0; ks < 8; ++ks) qf[ks] = *(const f16x8*)(qp + ks * 32);
    }

    f32x4 Oacc[16];
#pragma unroll
    for (int i = 0; i < 16; ++i) Oacc[i] = f32x4{0.f, 0.f, 0.f, 0.f};
    float mrun[4], lsum[4];
#pragma unroll
    for (int r = 0; r < 4; ++r) { mrun[r] = -1e30f; lsum[r] = 0.f; }

    const f16* Hbase = Hf + b * S * 256;
    const f16* Vbase = Vt + b * 256 * S;

    // prologue: stage this group's tile 0
#pragma unroll
    for (int i = 0; i < 4; ++i) {
        f16x8 v = *(const f16x8*)(Hbase + (kbase + krow[i]) * 256 + kc[i] * 8);
        *(f16x8*)&KhS[g][krow[i]][kc[i] * 8] = v;
    }
    __syncthreads();

    const int NT = 2048 / 32;     // 64 key-tiles per group
    for (int t = 0; t < NT; ++t) {
        int kt = kbase + t * 32;

        // prefetch next K-hat tile into registers (latency hides under QK^T)
        f16x8 rgK[4];
        if (t + 1 < NT) {
#pragma unroll
            for (int i = 0; i < 4; ++i)
                rgK[i] = *(const f16x8*)(Hbase + (kt + 32 + krow[i]) * 256 + kc[i] * 8);
        }

        // scores: 16 q-rows x 32 keys, K=256
        f32x4 scA[2], scB[2];
        scA[0] = f32x4{0.f,0.f,0.f,0.f}; scA[1] = f32x4{0.f,0.f,0.f,0.f};
        scB[0] = f32x4{0.f,0.f,0.f,0.f}; scB[1] = f32x4{0.f,0.f,0.f,0.f};
        __builtin_amdgcn_s_setprio(1);
#pragma unroll
        for (int ks = 0; ks < 8; ks += 2) {
#pragma unroll
            for (int nf = 0; nf < 2; ++nf) {
                f16x8 kb0 = *(const f16x8*)&KhS[g][nf * 16 + lr][ks * 32 + lg * 8];
                f16x8 kb1 = *(const f16x8*)&KhS[g][nf * 16 + lr][(ks + 1) * 32 + lg * 8];
                scA[nf] = MFMA16(qf[ks], kb0, scA[nf]);
                scB[nf] = MFMA16(qf[ks + 1], kb1, scB[nf]);
            }
        }
        __builtin_amdgcn_s_setprio(0);
        f32x4 sc[2];
        sc[0] = scA[0] + scB[0];
        sc[1] = scA[1] + scB[1];

        __syncthreads();          // all group waves done READING tile t

        // commit prefetched tile t+1 (write waits only on its own vmcnt)
        if (t + 1 < NT) {
#pragma unroll
            for (int i = 0; i < 4; ++i)
                *(f16x8*)&KhS[g][krow[i]][kc[i] * 8] = rgK[i];
        }

        // ---- softmax with defer-max: no shuffles in steady state ----
        float mloc[4];
        int need = 0;
#pragma unroll
        for (int r = 0; r < 4; ++r) {
            mloc[r] = fmaxf(sc[0][r], sc[1][r]);
            need |= (mloc[r] > mrun[r] + 8.f) ? 1 : 0;
        }
        if (__any(need)) {        // rare: true max grew past threshold
            float corr[4];
#pragma unroll
            for (int r = 0; r < 4; ++r) {
                float mt = mloc[r];
#pragma unroll
                for (int msk = 1; msk <= 8; msk <<= 1) mt = fmaxf(mt, __shfl_xor(mt, msk));
                float mn = fmaxf(mrun[r], mt);
                corr[r] = __expf(mrun[r] - mn);
                mrun[r] = mn;
                lsum[r] *= corr[r];
            }
#pragma unroll
            for (int i = 0; i < 16; ++i) {
                f32x4 o = Oacc[i];
                o[0] *= corr[0]; o[1] *= corr[1]; o[2] *= corr[2]; o[3] *= corr[3];
                Oacc[i] = o;
            }
        }
#pragma unroll
        for (int r = 0; r < 4; ++r) {
            float p0 = __expf(sc[0][r] - mrun[r]);   // bounded by e^8
            float p1 = __expf(sc[1][r] - mrun[r]);
            lsum[r] += p0 + p1;                      // per-lane partial denom
            PS[w][lg * 4 + r][lr]      = (f16)p0;
            PS[w][lg * 4 + r][16 + lr] = (f16)p1;
        }

        // ---- PV: V fragments straight from global (L1/L2) ----
        {
            f16x8 pa = *(const f16x8*)&PS[w][lr][lg * 8];  // intra-wave LDS dep
            const f16* vp = Vbase + (size_t)lr * S + kt + lg * 8;
#pragma unroll
            for (int q4 = 0; q4 < 4; ++q4) {
                f16x8 vb[4];
#pragma unroll
                for (int j = 0; j < 4; ++j)
                    vb[j] = *(const f16x8*)(vp + (size_t)(q4 * 4 + j) * 16 * S);
                __builtin_amdgcn_s_setprio(1);
#pragma unroll
                for (int j = 0; j < 4; ++j)
                    Oacc[q4 * 4 + j] = MFMA16(pa, vb[j], Oacc[q4 * 4 + j]);
                __builtin_amdgcn_s_setprio(0);
            }
        }

        __syncthreads();          // tile t+1 written & visible for next iter
    }

    // ---- epilogue: reduce denominators, merge the two key-groups in LDS ----
    float lrun[4];
#pragma unroll
    for (int r = 0; r < 4; ++r) {
        float s = lsum[r];
#pragma unroll
        for (int msk = 1; msk <= 8; msk <<= 1) s += __shfl_xor(s, msk);
        lrun[r] = s;
    }
    __syncthreads();              // loop LDS dead; safe to overlay

    if (lr == 0) {
#pragma unroll
        for (int r = 0; r < 4; ++r) {
            ML[w][lg * 4 + r][0] = mrun[r];
            ML[w][lg * 4 + r][1] = lrun[r];
        }
    }
    __syncthreads();

    float partM[4], partL[4];
#pragma unroll
    for (int r = 0; r < 4; ++r) {
        partM[r] = ML[w ^ 4][lg * 4 + r][0];
        partL[r] = ML[w ^ 4][lg * 4 + r][1];
    }
    float w0[4], w1[4];   // g0: w0 = e0*invd, w1 = invd.   g1: w1 = e1.
    if (g == 0) {
#pragma unroll
        for (int r = 0; r < 4; ++r) {
            float m  = fmaxf(mrun[r], partM[r]);
            float e0 = __expf(mrun[r] - m);
            float e1 = __expf(partM[r] - m);
            float invd = 1.0f / (lrun[r] * e0 + partL[r] * e1);
            w0[r] = e0 * invd;
            w1[r] = invd;
        }
    } else {
#pragma unroll
        for (int r = 0; r < 4; ++r) {
            float m = fmaxf(mrun[r], partM[r]);
            w1[r] = __expf(mrun[r] - m);
        }
    }

#pragma unroll
    for (int p = 0; p < 2; ++p) {
        if (g == 1) {
#pragma unroll
            for (int h = 0; h < 8; ++h) {
                int nf2 = p * 8 + h;
#pragma unroll
                for (int r = 0; r < 4; ++r)
                    MrgF[wg][lg * 4 + r][h * 16 + lr] = Oacc[nf2][r] * w1[r];
            }
        }
        __syncthreads();
        if (g == 0) {
#pragma unroll
            for (int h = 0; h < 8; ++h) {
                int nf2 = p * 8 + h;
#pragma unroll
                for (int r = 0; r < 4; ++r) {
                    float v = MrgF[wg][lg * 4 + r][h * 16 + lr];
                    int row = qb + lg * 4 + r;
                    Out[(b * S + row) * 256 + nf2 * 16 + lr] =
                        Oacc[nf2][r] * w0[r] + v * w1[r];
                }
            }
        }
        __syncthreads();
    }
}

// ---------------------------------------------------------------------------
extern "C" void kernel_launch(void* const* d_in, const int* in_sizes, int n_in,
                              void* d_out, int out_size, void* d_ws, size_t ws_size,
                              hipStream_t stream)
{
    const float* query = (const float*)d_in[0];
    const float* value = (const float*)d_in[1];
    const float* Wq    = (const float*)d_in[2];
    const float* bq    = (const float*)d_in[3];
    const float* Wk    = (const float*)d_in[4];
    const float* bk    = (const float*)d_in[5];
    const float* Wv    = (const float*)d_in[6];
    const float* bv    = (const float*)d_in[7];
    const float* Wr    = (const float*)d_in[8];
    const float* br    = (const float*)d_in[9];
    float* out = (float*)d_out;

    char* ws = (char*)d_ws;
    size_t off = 0;
    auto alloc = [&](size_t bytes) -> char* {
        char* p = ws + off;
        off += (bytes + 255) & ~(size_t)255;
        return p;
    };
    f16* WqT = (f16*)alloc((size_t)65536 * 2);
    f16* WkT = (f16*)alloc((size_t)65536 * 2);
    f16* WvT = (f16*)alloc((size_t)65536 * 2);
    f16* WrT = (f16*)alloc((size_t)65536 * 2);
    f16* Qf  = (f16*)alloc((size_t)NB * S * 256 * 2);
    f16* Kf  = (f16*)alloc((size_t)NB * S * 256 * 2);
    f16* Hf  = (f16*)alloc((size_t)NB * S * 256 * 2);
    f16* VtF = (f16*)alloc((size_t)NB * S * 256 * 2);
    (void)ws_size; (void)in_sizes; (void)n_in; (void)out_size;

    wconv_kernel<<<256, 256, 0, stream>>>(Wq, WqT);
    wconv_kernel<<<256, 256, 0, stream>>>(Wk, WkT);
    wconv_kernel<<<256, 256, 0, stream>>>(Wv, WvT);
    wconv_kernel<<<256, 256, 0, stream>>>(Wr, WrT);

    // Q = query @ Wq + bq           (f16 row-major)
    proj_kernel<0, 0><<<512, 256, 0, stream>>>(query, nullptr, WqT, bq, Qf);
    // K = value @ Wk + bk           (f16 row-major)
    proj_kernel<0, 0><<<512, 256, 0, stream>>>(value, nullptr, WkT, bk, Kf);
    // Khat = cos(K @ Wr + br)       (f16 row-major)
    proj_kernel<1, 1><<<512, 256, 0, stream>>>(nullptr, Kf, WrT, br, Hf);
    // V^T = (value @ Wv + bv)^T     (f16, [b][d][s])
    proj_kernel<0, 2><<<512, 256, 0, stream>>>(value, nullptr, WvT, bv, VtF);

    // flash attention with in-block key split + merge
    attn_kernel<<<256, 512, 0, stream>>>(Qf, Hf, VtF, out);
}